// Round 10
// baseline (149.362 us; speedup 1.0000x reference)
//
#include <hip/hip_runtime.h>
#include <cstdint>
#include <cstddef>

// Problem: B=8,S=2048,E=512,FFN=2048,Q=8 -> M=16384, K=2048, N=512.
// Round-10: intra-block split-K. 512 thr = 8 waves = 2 independent 4-wave
// K-groups (group ks does K-slices ks*32..ks*32+31, 32 iters) sharing one
// block. Grid 512 -> 2 blocks/CU = 16 waves/CU = 4 waves/SIMD, with R9's
// 64x64 wave tile / B-direct loads / XOR As image / ping-pong pipeline kept
// EXACTLY (isolates the occupancy variable R7/R8 contaminated). Partials
// combined via LDS (4 rounds, 16 KB), group 0 writes C + bias.

typedef __attribute__((ext_vector_type(8))) short s16x8;
typedef __attribute__((ext_vector_type(4))) float f32x4;

__device__ __forceinline__ unsigned short f2bf(float f) {
  unsigned int u = __float_as_uint(f);
  unsigned int r = u + 0x7fffu + ((u >> 16) & 1u);
  return (unsigned short)(r >> 16);
}

__device__ __forceinline__ void async_copy16(const void* g, void* l) {
  __builtin_amdgcn_global_load_lds(
      (const __attribute__((address_space(1))) void*)(uintptr_t)g,
      (__attribute__((address_space(3))) void*)(unsigned int)(uintptr_t)l,
      16, 0, 0);
}

// ---------------------------------------------------------------------------
// Kernel 1: build w2b image. chunk ci = (nt*64+s)*1024 + nhi*64 + quad*16 +
// nlo; data = bf16(w2[n][s*32+quad*8 .. +7]). A wave's B-frag j at slice s is
// 64 contiguous chunks (1 KB coalesced) at (nt*64+s)*1024 + (w*4+j)*64.
// ---------------------------------------------------------------------------
__global__ __launch_bounds__(256) void k_w2(const float* __restrict__ w2,
                                            unsigned short* __restrict__ img) {
  const int n = blockIdx.x;   // 0..511
  const int t = threadIdx.x;
  const int s = t >> 2, quad = t & 3;
  const float* src = w2 + (size_t)n * 2048 + t * 8;  // coalesced read
  float4 a = *(const float4*)src;
  float4 b = *(const float4*)(src + 4);
  uint4 pk;
  pk.x = f2bf(a.x) | ((unsigned)f2bf(a.y) << 16);
  pk.y = f2bf(a.z) | ((unsigned)f2bf(a.w) << 16);
  pk.z = f2bf(b.x) | ((unsigned)f2bf(b.y) << 16);
  pk.w = f2bf(b.z) | ((unsigned)f2bf(b.w) << 16);
  const int nt = n >> 8, nl = n & 255, nhi = nl >> 4, nlo = nl & 15;
  const size_t ci = (size_t)(nt * 64 + s) * 1024 + nhi * 64 + quad * 16 + nlo;
  *(uint4*)(img + ci * 8) = pk;
}

// ---------------------------------------------------------------------------
// Kernel 2 (fused): C[m][n] = sum_k relu(z[m]·w1[k]+b1[k]) * w2[n][k] + b2[n]
// ---------------------------------------------------------------------------
__global__ __launch_bounds__(512, 2) void k_fused(
    const float* __restrict__ x, const float* __restrict__ ry,
    const float* __restrict__ w1, const float* __restrict__ b1,
    const unsigned short* __restrict__ w2b, const float* __restrict__ b2,
    float* __restrict__ C) {
  __shared__ unsigned short As[2][2][64 * 32];  // [ks][buf] XOR images, 16 KB
  __shared__ float b1s[2048];                   // 8 KB
  __shared__ f32x4 red[1024];                   // 16 KB partial-sum buffer

  const int t = threadIdx.x;  // 0..511
  const int lane = t & 63;
  const int w = t >> 6;   // 0..7
  const int ks = w >> 2;  // K-group: 0 or 1
  const int wl = w & 3;   // wave within group -> wn = wl*64
  const int tg = t & 255; // thread within group
  const int mt = (int)(blockIdx.x >> 1);
  const int nt = (int)(blockIdx.x & 1);
  const int r0 = mt * 64;
  const int c0 = nt * 256;
  const int fp = tg & 15;  // f-pair index within the 32-wide K-step
  const int rq = tg >> 4;  // row-quad 0..15: rows rq*4 .. rq*4+3
  const int fr = lane & 15;
  const int quad = lane >> 4;

  // ---- z for this thread's 4 rows (both groups: same rows) ----
  float zr[4][8];
  {
    float4 ra = *(const float4*)ry;
    float4 rb = *(const float4*)(ry + 4);
    float cy[8] = {__cosf(ra.x), __cosf(ra.y), __cosf(ra.z), __cosf(ra.w),
                   __cosf(rb.x), __cosf(rb.y), __cosf(rb.z), __cosf(rb.w)};
#pragma unroll
    for (int r = 0; r < 4; ++r) {
      const float* xr = x + (size_t)(r0 + rq * 4 + r) * 512;
      float4 x0 = *(const float4*)xr;
      float4 x1 = *(const float4*)(xr + 4);
      zr[r][0] = __cosf(x0.x) * cy[0];
      zr[r][1] = __cosf(x0.y) * cy[1];
      zr[r][2] = __cosf(x0.z) * cy[2];
      zr[r][3] = __cosf(x0.w) * cy[3];
      zr[r][4] = __cosf(x1.x) * cy[4];
      zr[r][5] = __cosf(x1.y) * cy[5];
      zr[r][6] = __cosf(x1.z) * cy[6];
      zr[r][7] = __cosf(x1.w) * cy[7];
    }
  }
  __builtin_amdgcn_sched_barrier(0);

  // ---- group-local bases: slices sg = ks*32 + s_local ----
  const char* gBb =
      (const char*)w2b +
      (((size_t)nt * 64 + (size_t)ks * 32) * 1024 + (size_t)wl * 256 +
       (size_t)quad * 16 + fr) * 16;
  const float* w1g = w1 + (size_t)ks * 8192;       // 32 slices * 256 floats
  const float* b1g = b1s + (size_t)ks * 1024;      // 32 slices * 32 floats
#define LOADB(S, D)                                \
  {                                                \
    const char* p_ = gBb + (size_t)(S) * 16384;    \
    D[0] = *(const s16x8*)(p_);                    \
    D[1] = *(const s16x8*)(p_ + 1024);             \
    D[2] = *(const s16x8*)(p_ + 2048);             \
    D[3] = *(const s16x8*)(p_ + 3072);             \
  }

  // ---- prologue: b1s async (512 chunks, 1/thread); B(0); w1 slices 0,1 ----
  async_copy16(b1 + (size_t)t * 4, (char*)b1s + (size_t)t * 16);
  s16x8 Bp[4], Bq[4];
  LOADB(0, Bp);
  f32x4 wA0, wA1, wA2, wA3, wB0, wB1, wB2, wB3;
  {
    const f32x4* p0 = (const f32x4*)(w1g + fp * 16);  // group slice 0
    wA0 = p0[0]; wA1 = p0[1]; wA2 = p0[2]; wA3 = p0[3];
    const f32x4* p1 = (const f32x4*)(w1g + 256 + fp * 16);  // group slice 1
    wB0 = p1[0]; wB1 = p1[1]; wB2 = p1[2]; wB3 = p1[3];
  }
  asm volatile("s_waitcnt vmcnt(0) lgkmcnt(0)" ::: "memory");
  __builtin_amdgcn_sched_barrier(0);
  __builtin_amdgcn_s_barrier();  // b1s visible

  // ---- act: thread (rq,fp) -> rows rq*4..+3, k-pair fp (R6/R9-verified) ----
  const int q0 = rq & 1;
  const int koct = fp >> 2, fpl = fp & 3;
  const int sA_off = ((koct ^ ((rq * 2) & 3)) << 4) + fpl * 4;      // rows 0,1
  const int sB_off = ((koct ^ ((rq * 2 + 1) & 3)) << 4) + fpl * 4;  // rows 2,3
  const int rw0 = ((rq * 4 + 0) ^ q0) * 64;
  const int rw1 = ((rq * 4 + 1) ^ q0) * 64;
  const int rw2 = ((rq * 4 + 2) ^ q0) * 64;
  const int rw3 = ((rq * 4 + 3) ^ q0) * 64;
  char* asg = (char*)As + (size_t)ks * 8192;

  auto act = [&](int s, int buf, const f32x4& v0, const f32x4& v1,
                 const f32x4& v2, const f32x4& v3) {
    const float bb0 = b1g[s * 32 + fp * 2];
    const float bb1 = b1g[s * 32 + fp * 2 + 1];
    unsigned int u0, u1, u2, u3;
#define ACT_ROW(R, UD)                                                      \
  {                                                                         \
    float h0 = bb0, h1 = bb1;                                               \
    h0 += zr[R][0] * v0[0]; h1 += zr[R][0] * v2[0];                         \
    h0 += zr[R][1] * v0[1]; h1 += zr[R][1] * v2[1];                         \
    h0 += zr[R][2] * v0[2]; h1 += zr[R][2] * v2[2];                         \
    h0 += zr[R][3] * v0[3]; h1 += zr[R][3] * v2[3];                         \
    h0 += zr[R][4] * v1[0]; h1 += zr[R][4] * v3[0];                         \
    h0 += zr[R][5] * v1[1]; h1 += zr[R][5] * v3[1];                         \
    h0 += zr[R][6] * v1[2]; h1 += zr[R][6] * v3[2];                         \
    h0 += zr[R][7] * v1[3]; h1 += zr[R][7] * v3[3];                         \
    h0 = fmaxf(h0, 0.0f);                                                   \
    h1 = fmaxf(h1, 0.0f);                                                   \
    asm("v_cvt_pk_bf16_f32 %0, %1, %2" : "=v"(UD) : "v"(h0), "v"(h1));      \
  }
    ACT_ROW(0, u0) ACT_ROW(1, u1) ACT_ROW(2, u2) ACT_ROW(3, u3)
#undef ACT_ROW
    char* base = asg + buf * 4096;
    *(unsigned int*)(base + rw0 + sA_off) = q0 ? u1 : u0;
    *(unsigned int*)(base + rw1 + sA_off) = q0 ? u0 : u1;
    *(unsigned int*)(base + rw2 + sB_off) = q0 ? u3 : u2;
    *(unsigned int*)(base + rw3 + sB_off) = q0 ? u2 : u3;
  };

  act(0, 0, wA0, wA1, wA2, wA3);  // group's As[0]
  asm volatile("s_waitcnt lgkmcnt(0)" ::: "memory");
  __builtin_amdgcn_sched_barrier(0);
  __builtin_amdgcn_s_barrier();  // publish As[0] (both groups)

  // frag pointer: row = i*16+fr, koct = quad (XOR image)
  const int wn = wl * 64;
  const char* pAb = asg + fr * 64 + ((quad ^ ((fr >> 1) & 3)) << 4);

  f32x4 acc[4][4];
#pragma unroll
  for (int i = 0; i < 4; ++i)
#pragma unroll
    for (int j = 0; j < 4; ++j) acc[i][j] = (f32x4){0.f, 0.f, 0.f, 0.f};

// Per iter (R9 body, 32 iters/group): issue B(kt+1)->BL, w1(kt+2)->WL;
// vmcnt(8) => B(kt)/w1(kt+1) ready; af reads; act(kt+1); lgkm(0); MFMA; bar.
#define BODY(KT, BU, BL, WU0, WU1, WU2, WU3, WL0, WL1, WL2, WL3, BPRE,      \
             WPRE, ACTG, VMC)                                               \
  {                                                                         \
    if (BPRE) LOADB((KT) + 1, BL);                                          \
    if (WPRE) {                                                             \
      const f32x4* wp =                                                     \
          (const f32x4*)(w1g + (size_t)((KT) + 2) * 256 + fp * 16);         \
      WL0 = wp[0]; WL1 = wp[1]; WL2 = wp[2]; WL3 = wp[3];                   \
    }                                                                       \
    asm volatile("s_waitcnt vmcnt(" VMC ")" ::: "memory");                  \
    __builtin_amdgcn_sched_barrier(0);                                      \
    s16x8 af[4];                                                            \
    {                                                                       \
      const char* pA = pAb + ((KT) & 1) * 4096;                             \
      af[0] = *(const s16x8*)(pA);                                          \
      af[1] = *(const s16x8*)(pA + 1024);                                   \
      af[2] = *(const s16x8*)(pA + 2048);                                   \
      af[3] = *(const s16x8*)(pA + 3072);                                   \
    }                                                                       \
    if (ACTG) act((KT) + 1, ((KT) + 1) & 1, WU0, WU1, WU2, WU3);            \
    asm volatile("s_waitcnt lgkmcnt(0)" ::: "memory");                      \
    __builtin_amdgcn_sched_barrier(0);                                      \
    __builtin_amdgcn_s_setprio(1);                                          \
    _Pragma("unroll") for (int i = 0; i < 4; ++i)                           \
        _Pragma("unroll") for (int j = 0; j < 4; ++j) acc[i][j] =           \
        __builtin_amdgcn_mfma_f32_16x16x32_bf16(af[i], BU[j], acc[i][j],    \
                                                0, 0, 0);                   \
    __builtin_amdgcn_s_setprio(0);                                          \
    __builtin_amdgcn_s_barrier();                                           \
  }

  for (int kt = 0; kt < 30; kt += 2) {
    BODY(kt, Bp, Bq, wB0, wB1, wB2, wB3, wA0, wA1, wA2, wA3, true, true,
         true, "8");
    BODY(kt + 1, Bq, Bp, wA0, wA1, wA2, wA3, wB0, wB1, wB2, wB3, true, true,
         true, "8");
  }
  // tail: 30 (load B31, act 31, no w1 prefetch), 31 (MFMA only)
  BODY(30, Bp, Bq, wB0, wB1, wB2, wB3, wA0, wA1, wA2, wA3, true, false, true,
       "8");
  BODY(31, Bq, Bp, wA0, wA1, wA2, wA3, wB0, wB1, wB2, wB3, false, false,
       false, "0");
#undef BODY
#undef LOADB

  // ---- combine K-half partials via LDS: group1 -> red -> group0 adds ----
#pragma unroll
  for (int i = 0; i < 4; ++i) {
    if (ks) {
      red[tg * 4 + 0] = acc[i][0];
      red[tg * 4 + 1] = acc[i][1];
      red[tg * 4 + 2] = acc[i][2];
      red[tg * 4 + 3] = acc[i][3];
    }
    __syncthreads();
    if (!ks) {
      acc[i][0] += red[tg * 4 + 0];
      acc[i][1] += red[tg * 4 + 1];
      acc[i][2] += red[tg * 4 + 2];
      acc[i][3] += red[tg * 4 + 3];
    }
    __syncthreads();
  }

  // epilogue (group 0 only): C/D layout col = lane&15, row = quad*4 + reg
  if (ks == 0) {
    float bias[4];
#pragma unroll
    for (int j = 0; j < 4; ++j) bias[j] = b2[c0 + wn + j * 16 + fr];
#pragma unroll
    for (int i = 0; i < 4; ++i) {
      const int rbase = r0 + i * 16 + quad * 4;
#pragma unroll
      for (int rr = 0; rr < 4; ++rr) {
        float* crow = C + (size_t)(rbase + rr) * 512;
#pragma unroll
        for (int j = 0; j < 4; ++j)
          crow[c0 + wn + j * 16 + fr] = acc[i][j][rr] + bias[j];
      }
    }
  }
}

// ---------------------------------------------------------------------------
// Emergency fallback (only if ws_size is tiny): fully fused fp32, 1 row/block.
// ---------------------------------------------------------------------------
__global__ __launch_bounds__(256) void k_naive(
    const float* __restrict__ x, const float* __restrict__ ry,
    const float* __restrict__ w1, const float* __restrict__ b1,
    const float* __restrict__ w2, const float* __restrict__ b2,
    float* __restrict__ out) {
  __shared__ float zsh[8];
  __shared__ float acts[2048];
  const int r = blockIdx.x;
  const int t = threadIdx.x;
  if (t < 8) zsh[t] = __cosf(x[(size_t)r * 512 + t]) * __cosf(ry[t]);
  __syncthreads();
  float z[8];
#pragma unroll
  for (int q = 0; q < 8; ++q) z[q] = zsh[q];
#pragma unroll
  for (int i = 0; i < 8; ++i) {
    const int f = t * 8 + i;
    const float* wr = w1 + (size_t)f * 8;
    float4 a = *(const float4*)wr;
    float4 b = *(const float4*)(wr + 4);
    float h = b1[f] + z[0] * a.x + z[1] * a.y + z[2] * a.z + z[3] * a.w +
              z[4] * b.x + z[5] * b.y + z[6] * b.z + z[7] * b.w;
    acts[f] = fmaxf(h, 0.0f);
  }
  __syncthreads();
  for (int ee = 0; ee < 2; ++ee) {
    const int e = t + ee * 256;
    const float* wr = w2 + (size_t)e * 2048;
    float acc = b2[e];
    for (int f = 0; f < 2048; f += 4) {
      float4 wv = *(const float4*)(wr + f);
      float4 av = *(const float4*)(acts + f);
      acc += av.x * wv.x + av.y * wv.y + av.z * wv.z + av.w * wv.w;
    }
    out[(size_t)r * 512 + e] = acc;
  }
}

extern "C" void kernel_launch(void* const* d_in, const int* in_sizes, int n_in,
                              void* d_out, int out_size, void* d_ws,
                              size_t ws_size, hipStream_t stream) {
  const float* x  = (const float*)d_in[0];
  const float* ry = (const float*)d_in[1];
  const float* w1 = (const float*)d_in[2];
  const float* b1 = (const float*)d_in[3];
  const float* w2 = (const float*)d_in[4];
  const float* b2 = (const float*)d_in[5];
  float* out = (float*)d_out;

  const size_t w2b_bytes = (size_t)512 * 2048 * 2;  // 2 MB bf16 w2 image
  if (ws_size < w2b_bytes) {
    k_naive<<<dim3(16384), dim3(256), 0, stream>>>(x, ry, w1, b1, w2, b2, out);
    return;
  }
  unsigned short* w2b = (unsigned short*)d_ws;
  k_w2<<<dim3(512), dim3(256), 0, stream>>>(w2, w2b);
  k_fused<<<dim3(512), dim3(512), 0, stream>>>(x, ry, w1, b1, w2b, b2, out);
}